// Round 5
// baseline (115.362 us; speedup 1.0000x reference)
//
#include <hip/hip_runtime.h>
#include <math.h>

// VQ quantizer: x [512,256,12] fp32, codebook [512,12] fp32.
// Outputs (concat fp32): quantized_st [512*256*12], indices-as-float [512*256], loss [1].
namespace {
constexpr int KCB   = 512;
constexpr int DIM   = 12;
constexpr int NTOK  = 512 * 256;       // 131072
constexpr int QSIZE = NTOK * DIM;      // 1572864
constexpr int NSPLIT = 8;              // waves per block == K chunks
constexpr int KCHUNK = KCB / NSPLIT;   // 64 codes per wave
constexpr int TPT    = 8;              // tokens per thread (amortize LDS broadcast)
constexpr int TOKS_PER_BLOCK = 64 * TPT;        // 512
constexpr int NBLK   = NTOK / TOKS_PER_BLOCK;   // 256 blocks x 512 thr
constexpr int WVEC_FLOATS = KCB * DIM;          // 6144 (tight 48B rows)
constexpr int CB_FLOATS   = WVEC_FLOATS + KCB;  // + w2[512] = 6656 floats = 26.6 KB
constexpr int CB_F4       = CB_FLOATS / 4;      // 1664

// ws layout: [wvec 512x12 tight][w2 512]; also zero the loss slot (d_out is
// re-poisoned to 0xAA before every launch).
__global__ __launch_bounds__(256) void pack_cb(const float* __restrict__ cb,
                                               float* __restrict__ ws,
                                               float* __restrict__ out) {
    int k = blockIdx.x * blockDim.x + threadIdx.x;
    if (k == 0) out[QSIZE + NTOK] = 0.f;
    if (k >= KCB) return;
    float w[DIM];
#pragma unroll
    for (int d = 0; d < DIM; ++d) w[d] = cb[k * DIM + d];
    float w2 = 0.f;
#pragma unroll
    for (int d = 0; d < DIM; ++d) w2 += w[d] * w[d];   // same rounding as R1-R4
#pragma unroll
    for (int d = 0; d < DIM; ++d) ws[k * DIM + d] = w[d];
    ws[WVEC_FLOATS + k] = w2;
}

// EXACT score sequence validated R1-R4 (absmax 0.0 vs numpy). Do not reorder.
__device__ inline float code_score(const float (&xv)[DIM], float x2,
                                   const float4& c0, const float4& c1,
                                   const float4& c2, float w2k) {
    float xw = 0.f;
    xw = fmaf(xv[0],  c0.x, xw);
    xw = fmaf(xv[1],  c0.y, xw);
    xw = fmaf(xv[2],  c0.z, xw);
    xw = fmaf(xv[3],  c0.w, xw);
    xw = fmaf(xv[4],  c1.x, xw);
    xw = fmaf(xv[5],  c1.y, xw);
    xw = fmaf(xv[6],  c1.z, xw);
    xw = fmaf(xv[7],  c1.w, xw);
    xw = fmaf(xv[8],  c2.x, xw);
    xw = fmaf(xv[9],  c2.y, xw);
    xw = fmaf(xv[10], c2.z, xw);
    xw = fmaf(xv[11], c2.w, xw);
    return fmaf(-2.f, xw, x2) + w2k;
}

// Block = 512 tokens x 8 K-splits (8 waves). Each wave scans 64 codes for all
// 512 tokens (8 tokens/thread): per 4-code group = 13 ds_read_b128 (156 LDS
// cyc, CU-shared pipe) vs 544 VALU instr (272 cyc/CU-share at 4 SIMDs) ->
// VALU-bound with 1.7x margin (R4 was LDS-pipe-bound at TPT=2). Low occupancy
// (2 waves/SIMD) is fine: 32 independent fmaf chains per group saturate issue.
__global__ __launch_bounds__(512, 2) void vq_main(const float* __restrict__ x,
                                                  const float* __restrict__ cb,
                                                  const float* __restrict__ pk,
                                                  float* __restrict__ out) {
    // 32 KB: staging view (26.6 KB) first, aliased by the 8x512 u64 reduction
    __shared__ unsigned long long smem[NSPLIT * TOKS_PER_BLOCK];  // 32768 B
    float* lds = (float*)smem;
    const int tid  = threadIdx.x;
    const int lane = tid & 63;
    const int s = __builtin_amdgcn_readfirstlane(tid >> 6);  // K-chunk id
    const int tbase = blockIdx.x * TOKS_PER_BLOCK;

    // stage packed codebook global->LDS (coalesced float4)
    {
        float4* l4 = (float4*)lds;
        const float4* g4 = (const float4*)pk;
        for (int i = tid; i < CB_F4; i += 512) l4[i] = g4[i];
    }

    // load this thread's 8 tokens (coalesced: lane-contiguous 48B rows)
    float xs[TPT][DIM];
    float x2[TPT];
#pragma unroll
    for (int j = 0; j < TPT; ++j) {
        const float4* xp = (const float4*)(x + (size_t)(tbase + j * 64 + lane) * DIM);
        float4 a0 = xp[0], a1 = xp[1], a2 = xp[2];
        xs[j][0] = a0.x; xs[j][1] = a0.y; xs[j][2]  = a0.z; xs[j][3]  = a0.w;
        xs[j][4] = a1.x; xs[j][5] = a1.y; xs[j][6]  = a1.z; xs[j][7]  = a1.w;
        xs[j][8] = a2.x; xs[j][9] = a2.y; xs[j][10] = a2.z; xs[j][11] = a2.w;
        float t2 = 0.f;
#pragma unroll
        for (int d = 0; d < DIM; ++d) t2 = fmaf(xs[j][d], xs[j][d], t2);
        x2[j] = t2;
    }

    __syncthreads();   // codebook resident

    float best[TPT];
    int   bi[TPT];
#pragma unroll
    for (int j = 0; j < TPT; ++j) { best[j] = INFINITY; bi[j] = 0; }

    const int k0 = s * KCHUNK;
    const float* w2v = lds + WVEC_FLOATS;
#pragma unroll 1                      // keep body ~2.5KB: I$-safe, regs bounded
    for (int g = 0; g < KCHUNK / 4; ++g) {   // 16 groups of 4 codes
        float4 w2q = ((const float4*)w2v)[(k0 >> 2) + g];
        const float* cbase = lds + (size_t)(k0 + 4 * g) * DIM;
#pragma unroll
        for (int u = 0; u < 4; ++u) {
            float4 c0 = *(const float4*)(cbase + u * DIM + 0);
            float4 c1 = *(const float4*)(cbase + u * DIM + 4);
            float4 c2 = *(const float4*)(cbase + u * DIM + 8);
            float w2k = (u == 0) ? w2q.x : (u == 1) ? w2q.y : (u == 2) ? w2q.z : w2q.w;
            const int k = k0 + 4 * g + u;
#pragma unroll
            for (int j = 0; j < TPT; ++j) {
                float d = code_score(xs[j], x2[j], c0, c1, c2, w2k);
                bool c = d < best[j];          // strict < => first occurrence
                best[j] = c ? d : best[j];
                bi[j]   = c ? k : bi[j];
            }
        }
    }

    // cross-wave argmin: u64 (monotone(score), k) unsigned-min == exact
    // lexicographic first-occurrence argmin (validated R2-R4).
    auto mkkey = [](float v, int k) {
        unsigned su = __float_as_uint(v);
        su = (su & 0x80000000u) ? ~su : (su | 0x80000000u);
        return ((unsigned long long)su << 32) | (unsigned)k;
    };
    __syncthreads();   // done reading codebook before aliasing overwrite
#pragma unroll
    for (int j = 0; j < TPT; ++j)
        smem[s * TOKS_PER_BLOCK + j * 64 + lane] = mkkey(best[j], bi[j]);
    __syncthreads();

    // wave s finalizes tokens s*64+lane — it holds their xs in xs[s].
    {
        const int tok = s * 64 + lane;
        unsigned long long m = smem[tok];
#pragma unroll
        for (int r = 1; r < NSPLIT; ++r) {
            unsigned long long v = smem[r * TOKS_PER_BLOCK + tok];
            m = v < m ? v : m;
        }
        const int bid = (int)(m & 0xffffffffULL);
        unsigned eu = (unsigned)(m >> 32);
        unsigned orig = (eu & 0x80000000u) ? (eu ^ 0x80000000u) : ~eu;
        const float bsc = __uint_as_float(orig);
        const int t = tbase + tok;

        // pick xs[s] via uniform unrolled branch (no dynamic reg indexing)
        float xv[DIM];
#pragma unroll
        for (int j = 0; j < TPT; ++j)
            if (j == s) {
#pragma unroll
                for (int d = 0; d < DIM; ++d) xv[d] = xs[j][d];
            }

        const float4* wrow = (const float4*)(cb + (size_t)bid * DIM);  // 48B rows, 16B aligned
        float4 q0 = wrow[0], q1 = wrow[1], q2 = wrow[2];
        float qs[DIM] = {q0.x, q0.y, q0.z, q0.w, q1.x, q1.y, q1.z, q1.w,
                         q2.x, q2.y, q2.z, q2.w};

        float4* qo = (float4*)(out + (size_t)t * DIM);
        float4 r0, r1, r2;
        r0.x = xv[0] + (qs[0] - xv[0]);    r0.y = xv[1] + (qs[1] - xv[1]);
        r0.z = xv[2] + (qs[2] - xv[2]);    r0.w = xv[3] + (qs[3] - xv[3]);
        r1.x = xv[4] + (qs[4] - xv[4]);    r1.y = xv[5] + (qs[5] - xv[5]);
        r1.z = xv[6] + (qs[6] - xv[6]);    r1.w = xv[7] + (qs[7] - xv[7]);
        r2.x = xv[8] + (qs[8] - xv[8]);    r2.y = xv[9] + (qs[9] - xv[9]);
        r2.z = xv[10] + (qs[10] - xv[10]); r2.w = xv[11] + (qs[11] - xv[11]);
        qo[0] = r0; qo[1] = r1; qo[2] = r2;

        out[QSIZE + t] = (float)bid;

        // loss: sum_d(q-x)^2 == best score (~1e-8 rel apart; threshold ~2%)
        float ls = bsc * (1.25f / (float)QSIZE);
#pragma unroll
        for (int off = 32; off > 0; off >>= 1) ls += __shfl_down(ls, off);
        if (lane == 0) atomicAdd(out + QSIZE + NTOK, ls);
    }
}
} // namespace

extern "C" void kernel_launch(void* const* d_in, const int* in_sizes, int n_in,
                              void* d_out, int out_size, void* d_ws, size_t ws_size,
                              hipStream_t stream) {
    const float* x  = (const float*)d_in[0];
    const float* cb = (const float*)d_in[1];
    float* out = (float*)d_out;
    float* pk  = (float*)d_ws;   // 26.6 KB workspace

    pack_cb<<<2, 256, 0, stream>>>(cb, pk, out);
    vq_main<<<NBLK, 512, 0, stream>>>(x, cb, pk, out);
}

// Round 6
// 113.716 us; speedup vs baseline: 1.0145x; 1.0145x over previous
//
#include <hip/hip_runtime.h>
#include <math.h>

// VQ quantizer: x [512,256,12] fp32, codebook [512,12] fp32.
// Outputs (concat fp32): quantized_st [512*256*12], indices-as-float [512*256], loss [1].
namespace {
constexpr int KCB   = 512;
constexpr int DIM   = 12;
constexpr int NTOK  = 512 * 256;       // 131072
constexpr int QSIZE = NTOK * DIM;      // 1572864
constexpr int NSPLIT = 8;              // waves per block == K chunks
constexpr int KCHUNK = KCB / NSPLIT;   // 64 codes per wave
constexpr int TPT    = 8;              // tokens per thread (amortize LDS broadcast)
constexpr int TOKS_PER_BLOCK = 64 * TPT;        // 512
constexpr int NBLK   = NTOK / TOKS_PER_BLOCK;   // 256 blocks x 512 thr
constexpr int WVEC_FLOATS = KCB * DIM;          // 6144 (tight 48B rows)
constexpr int CB_FLOATS   = WVEC_FLOATS + KCB;  // + w2[512] = 6656 floats = 26.6 KB
constexpr int CB_F4       = CB_FLOATS / 4;      // 1664

// ws layout: [wvec 512x12 tight][w2 512]; also zero the loss slot (d_out is
// re-poisoned to 0xAA before every launch).
__global__ __launch_bounds__(256) void pack_cb(const float* __restrict__ cb,
                                               float* __restrict__ ws,
                                               float* __restrict__ out) {
    int k = blockIdx.x * blockDim.x + threadIdx.x;
    if (k == 0) out[QSIZE + NTOK] = 0.f;
    if (k >= KCB) return;
    float w[DIM];
#pragma unroll
    for (int d = 0; d < DIM; ++d) w[d] = cb[k * DIM + d];
    float w2 = 0.f;
#pragma unroll
    for (int d = 0; d < DIM; ++d) w2 += w[d] * w[d];   // same rounding as R1-R5
#pragma unroll
    for (int d = 0; d < DIM; ++d) ws[k * DIM + d] = w[d];
    ws[WVEC_FLOATS + k] = w2;
}

// EXACT score sequence validated R1-R5 (absmax 0.0 vs numpy). Do not reorder.
__device__ inline float code_score(const float (&xv)[DIM], float x2,
                                   const float4& c0, const float4& c1,
                                   const float4& c2, float w2k) {
    float xw = 0.f;
    xw = fmaf(xv[0],  c0.x, xw);
    xw = fmaf(xv[1],  c0.y, xw);
    xw = fmaf(xv[2],  c0.z, xw);
    xw = fmaf(xv[3],  c0.w, xw);
    xw = fmaf(xv[4],  c1.x, xw);
    xw = fmaf(xv[5],  c1.y, xw);
    xw = fmaf(xv[6],  c1.z, xw);
    xw = fmaf(xv[7],  c1.w, xw);
    xw = fmaf(xv[8],  c2.x, xw);
    xw = fmaf(xv[9],  c2.y, xw);
    xw = fmaf(xv[10], c2.z, xw);
    xw = fmaf(xv[11], c2.w, xw);
    return fmaf(-2.f, xw, x2) + w2k;
}

// Block = 512 tokens x 8 K-splits (8 waves). Each wave scans 64 codes for all
// 512 tokens (8 tok/thread). Pipe arithmetic per CU: LDS 19968 cyc vs VALU
// 34.8K cyc/SIMD -> VALU-bound with 1.7x LDS margin.
// launch_bounds(512,1): R5's (512,2) made the compiler cap at 128 VGPRs for
// an occupancy the 256-block grid can't use, spilling xs[8][12] to scratch
// in the hot loop (WRITE_SIZE 6.7->15.4 MB). Cap 512 regs -> ~150-200 used,
// zero spills; grid gives 1 block/CU (8 waves) regardless.
__global__ __launch_bounds__(512, 1) void vq_main(const float* __restrict__ x,
                                                  const float* __restrict__ cb,
                                                  const float* __restrict__ pk,
                                                  float* __restrict__ out) {
    // 32 KB: staging view (26.6 KB) first, aliased by the 8x512 u64 reduction
    __shared__ unsigned long long smem[NSPLIT * TOKS_PER_BLOCK];  // 32768 B
    float* lds = (float*)smem;
    const int tid  = threadIdx.x;
    const int lane = tid & 63;
    const int s = __builtin_amdgcn_readfirstlane(tid >> 6);  // K-chunk id
    const int tbase = blockIdx.x * TOKS_PER_BLOCK;

    // stage packed codebook global->LDS (coalesced float4)
    {
        float4* l4 = (float4*)lds;
        const float4* g4 = (const float4*)pk;
        for (int i = tid; i < CB_F4; i += 512) l4[i] = g4[i];
    }

    // load this thread's 8 tokens (coalesced: lane-contiguous 48B rows)
    float xs[TPT][DIM];
    float x2[TPT];
#pragma unroll
    for (int j = 0; j < TPT; ++j) {
        const float4* xp = (const float4*)(x + (size_t)(tbase + j * 64 + lane) * DIM);
        float4 a0 = xp[0], a1 = xp[1], a2 = xp[2];
        xs[j][0] = a0.x; xs[j][1] = a0.y; xs[j][2]  = a0.z; xs[j][3]  = a0.w;
        xs[j][4] = a1.x; xs[j][5] = a1.y; xs[j][6]  = a1.z; xs[j][7]  = a1.w;
        xs[j][8] = a2.x; xs[j][9] = a2.y; xs[j][10] = a2.z; xs[j][11] = a2.w;
        float t2 = 0.f;
#pragma unroll
        for (int d = 0; d < DIM; ++d) t2 = fmaf(xs[j][d], xs[j][d], t2);
        x2[j] = t2;
    }

    __syncthreads();   // codebook resident

    float best[TPT];
    int   bi[TPT];
#pragma unroll
    for (int j = 0; j < TPT; ++j) { best[j] = INFINITY; bi[j] = 0; }

    const int k0 = s * KCHUNK;
    const float* w2v = lds + WVEC_FLOATS;
#pragma unroll 2                      // 2 groups in flight: ds_reads pipeline
    for (int g = 0; g < KCHUNK / 4; ++g) {   // 16 groups of 4 codes
        float4 w2q = ((const float4*)w2v)[(k0 >> 2) + g];
        const float* cbase = lds + (size_t)(k0 + 4 * g) * DIM;
#pragma unroll
        for (int u = 0; u < 4; ++u) {
            float4 c0 = *(const float4*)(cbase + u * DIM + 0);
            float4 c1 = *(const float4*)(cbase + u * DIM + 4);
            float4 c2 = *(const float4*)(cbase + u * DIM + 8);
            float w2k = (u == 0) ? w2q.x : (u == 1) ? w2q.y : (u == 2) ? w2q.z : w2q.w;
            const int k = k0 + 4 * g + u;
#pragma unroll
            for (int j = 0; j < TPT; ++j) {
                float d = code_score(xs[j], x2[j], c0, c1, c2, w2k);
                bool c = d < best[j];          // strict < => first occurrence
                best[j] = c ? d : best[j];
                bi[j]   = c ? k : bi[j];
            }
        }
    }

    // cross-wave argmin: u64 (monotone(score), k) unsigned-min == exact
    // lexicographic first-occurrence argmin (validated R2-R5).
    auto mkkey = [](float v, int k) {
        unsigned su = __float_as_uint(v);
        su = (su & 0x80000000u) ? ~su : (su | 0x80000000u);
        return ((unsigned long long)su << 32) | (unsigned)k;
    };
    __syncthreads();   // done reading codebook before aliasing overwrite
#pragma unroll
    for (int j = 0; j < TPT; ++j)
        smem[s * TOKS_PER_BLOCK + j * 64 + lane] = mkkey(best[j], bi[j]);
    __syncthreads();

    // wave s finalizes tokens s*64+lane — it holds their xs in xs[s].
    {
        const int tok = s * 64 + lane;
        unsigned long long m = smem[tok];
#pragma unroll
        for (int r = 1; r < NSPLIT; ++r) {
            unsigned long long v = smem[r * TOKS_PER_BLOCK + tok];
            m = v < m ? v : m;
        }
        const int bid = (int)(m & 0xffffffffULL);
        unsigned eu = (unsigned)(m >> 32);
        unsigned orig = (eu & 0x80000000u) ? (eu ^ 0x80000000u) : ~eu;
        const float bsc = __uint_as_float(orig);
        const int t = tbase + tok;

        // pick xs[s] via uniform unrolled branch (no dynamic reg indexing)
        float xv[DIM];
#pragma unroll
        for (int j = 0; j < TPT; ++j)
            if (j == s) {
#pragma unroll
                for (int d = 0; d < DIM; ++d) xv[d] = xs[j][d];
            }

        const float4* wrow = (const float4*)(cb + (size_t)bid * DIM);  // 48B rows, 16B aligned
        float4 q0 = wrow[0], q1 = wrow[1], q2 = wrow[2];
        float qs[DIM] = {q0.x, q0.y, q0.z, q0.w, q1.x, q1.y, q1.z, q1.w,
                         q2.x, q2.y, q2.z, q2.w};

        float4* qo = (float4*)(out + (size_t)t * DIM);
        float4 r0, r1, r2;
        r0.x = xv[0] + (qs[0] - xv[0]);    r0.y = xv[1] + (qs[1] - xv[1]);
        r0.z = xv[2] + (qs[2] - xv[2]);    r0.w = xv[3] + (qs[3] - xv[3]);
        r1.x = xv[4] + (qs[4] - xv[4]);    r1.y = xv[5] + (qs[5] - xv[5]);
        r1.z = xv[6] + (qs[6] - xv[6]);    r1.w = xv[7] + (qs[7] - xv[7]);
        r2.x = xv[8] + (qs[8] - xv[8]);    r2.y = xv[9] + (qs[9] - xv[9]);
        r2.z = xv[10] + (qs[10] - xv[10]); r2.w = xv[11] + (qs[11] - xv[11]);
        qo[0] = r0; qo[1] = r1; qo[2] = r2;

        out[QSIZE + t] = (float)bid;

        // loss: sum_d(q-x)^2 == best score (~1e-8 rel apart; threshold ~2%)
        float ls = bsc * (1.25f / (float)QSIZE);
#pragma unroll
        for (int off = 32; off > 0; off >>= 1) ls += __shfl_down(ls, off);
        if (lane == 0) atomicAdd(out + QSIZE + NTOK, ls);
    }
}
} // namespace

extern "C" void kernel_launch(void* const* d_in, const int* in_sizes, int n_in,
                              void* d_out, int out_size, void* d_ws, size_t ws_size,
                              hipStream_t stream) {
    const float* x  = (const float*)d_in[0];
    const float* cb = (const float*)d_in[1];
    float* out = (float*)d_out;
    float* pk  = (float*)d_ws;   // 26.6 KB workspace

    pack_cb<<<2, 256, 0, stream>>>(cb, pk, out);
    vq_main<<<NBLK, 512, 0, stream>>>(x, cb, pk, out);
}

// Round 7
// 107.705 us; speedup vs baseline: 1.0711x; 1.0558x over previous
//
#include <hip/hip_runtime.h>
#include <math.h>

// VQ quantizer: x [512,256,12] fp32, codebook [512,12] fp32.
// Outputs (concat fp32): quantized_st [512*256*12], indices-as-float [512*256], loss [1].
namespace {
constexpr int KCB   = 512;
constexpr int DIM   = 12;
constexpr int NTOK  = 512 * 256;       // 131072
constexpr int QSIZE = NTOK * DIM;      // 1572864
constexpr int NSPLIT = 8;              // waves per block == K chunks
constexpr int KCHUNK = KCB / NSPLIT;   // 64 codes per wave
constexpr int TPT    = 4;              // tokens/thread: xs[4][12]+transients ~105 VGPR
                                       // -> fits the allocator's hard 128 cap with NO
                                       // scratch spills (R5/R6: TPT=8 needed ~155,
                                       // spilled ~25 regs -> WRITE_SIZE 17MB, 60us)
constexpr int TOKS_PER_BLOCK = 64 * TPT;        // 256
constexpr int NBLK   = NTOK / TOKS_PER_BLOCK;   // 512 blocks x 512 thr = 2 blocks/CU
constexpr int WVEC_FLOATS = KCB * DIM;          // 6144 (tight 48B rows)
constexpr int CB_FLOATS   = WVEC_FLOATS + KCB;  // + w2[512] = 6656 floats = 26.6 KB
constexpr int CB_F4       = CB_FLOATS / 4;      // 1664
constexpr int SMEM_U64    = 3328;               // 26624 B: covers staging (26.6 KB)
                                                // and 8x256 u64 reduction (16 KB)

// ws layout: [wvec 512x12 tight][w2 512]; also zero the loss slot (d_out is
// re-poisoned to 0xAA before every launch).
__global__ __launch_bounds__(256) void pack_cb(const float* __restrict__ cb,
                                               float* __restrict__ ws,
                                               float* __restrict__ out) {
    int k = blockIdx.x * blockDim.x + threadIdx.x;
    if (k == 0) out[QSIZE + NTOK] = 0.f;
    if (k >= KCB) return;
    float w[DIM];
#pragma unroll
    for (int d = 0; d < DIM; ++d) w[d] = cb[k * DIM + d];
    float w2 = 0.f;
#pragma unroll
    for (int d = 0; d < DIM; ++d) w2 += w[d] * w[d];   // same rounding as R1-R6
#pragma unroll
    for (int d = 0; d < DIM; ++d) ws[k * DIM + d] = w[d];
    ws[WVEC_FLOATS + k] = w2;
}

// EXACT score sequence validated R1-R6 (absmax 0.0 vs numpy). Do not reorder.
__device__ inline float code_score(const float (&xv)[DIM], float x2,
                                   const float4& c0, const float4& c1,
                                   const float4& c2, float w2k) {
    float xw = 0.f;
    xw = fmaf(xv[0],  c0.x, xw);
    xw = fmaf(xv[1],  c0.y, xw);
    xw = fmaf(xv[2],  c0.z, xw);
    xw = fmaf(xv[3],  c0.w, xw);
    xw = fmaf(xv[4],  c1.x, xw);
    xw = fmaf(xv[5],  c1.y, xw);
    xw = fmaf(xv[6],  c1.z, xw);
    xw = fmaf(xv[7],  c1.w, xw);
    xw = fmaf(xv[8],  c2.x, xw);
    xw = fmaf(xv[9],  c2.y, xw);
    xw = fmaf(xv[10], c2.z, xw);
    xw = fmaf(xv[11], c2.w, xw);
    return fmaf(-2.f, xw, x2) + w2k;
}

// Block = 256 tokens x 8 K-splits (8 waves, 512 thr). Wave s scans its 64
// codes for all 256 tokens (4 tok/thread). Per-CU pipe model: LDS scan
// 2x1664 b128 x 12cyc = 40K cyc (16.6us) vs VALU 34.8K cyc/SIMD (14.5us)
// -> near-balanced, no spills, 16 waves/CU.
__global__ __launch_bounds__(512, 2) void vq_main(const float* __restrict__ x,
                                                  const float* __restrict__ cb,
                                                  const float* __restrict__ pk,
                                                  float* __restrict__ out) {
    __shared__ unsigned long long smem[SMEM_U64];   // staging view, then reduction
    float* lds = (float*)smem;
    const int tid  = threadIdx.x;
    const int lane = tid & 63;
    const int s = __builtin_amdgcn_readfirstlane(tid >> 6);  // K-chunk id
    const int tbase = blockIdx.x * TOKS_PER_BLOCK;

    // stage packed codebook global->LDS (coalesced float4, lane-distributed
    // ds_writes: only ~26 wave-instructions per block)
    {
        float4* l4 = (float4*)lds;
        const float4* g4 = (const float4*)pk;
        for (int i = tid; i < CB_F4; i += 512) l4[i] = g4[i];
    }

    // load this thread's 4 tokens (coalesced lane-contiguous 48B rows)
    float xs[TPT][DIM];
    float x2[TPT];
#pragma unroll
    for (int j = 0; j < TPT; ++j) {
        const float4* xp = (const float4*)(x + (size_t)(tbase + j * 64 + lane) * DIM);
        float4 a0 = xp[0], a1 = xp[1], a2 = xp[2];
        xs[j][0] = a0.x; xs[j][1] = a0.y; xs[j][2]  = a0.z; xs[j][3]  = a0.w;
        xs[j][4] = a1.x; xs[j][5] = a1.y; xs[j][6]  = a1.z; xs[j][7]  = a1.w;
        xs[j][8] = a2.x; xs[j][9] = a2.y; xs[j][10] = a2.z; xs[j][11] = a2.w;
        float t2 = 0.f;
#pragma unroll
        for (int d = 0; d < DIM; ++d) t2 = fmaf(xs[j][d], xs[j][d], t2);
        x2[j] = t2;
    }

    __syncthreads();   // codebook resident

    float best[TPT];
    int   bi[TPT];
#pragma unroll
    for (int j = 0; j < TPT; ++j) { best[j] = INFINITY; bi[j] = 0; }

    const int k0 = s * KCHUNK;
    const float* w2v = lds + WVEC_FLOATS;
#pragma unroll 2                      // 2 groups in flight: ds_reads pipeline
    for (int g = 0; g < KCHUNK / 4; ++g) {   // 16 groups of 4 codes
        float4 w2q = ((const float4*)w2v)[(k0 >> 2) + g];
        const float* cbase = lds + (size_t)(k0 + 4 * g) * DIM;
#pragma unroll
        for (int u = 0; u < 4; ++u) {
            float4 c0 = *(const float4*)(cbase + u * DIM + 0);
            float4 c1 = *(const float4*)(cbase + u * DIM + 4);
            float4 c2 = *(const float4*)(cbase + u * DIM + 8);
            float w2k = (u == 0) ? w2q.x : (u == 1) ? w2q.y : (u == 2) ? w2q.z : w2q.w;
            const int k = k0 + 4 * g + u;
#pragma unroll
            for (int j = 0; j < TPT; ++j) {
                float d = code_score(xs[j], x2[j], c0, c1, c2, w2k);
                bool c = d < best[j];          // strict < => first occurrence
                best[j] = c ? d : best[j];
                bi[j]   = c ? k : bi[j];
            }
        }
    }

    // cross-wave argmin: u64 (monotone(score), k) unsigned-min == exact
    // lexicographic first-occurrence argmin (validated R2-R6).
    auto mkkey = [](float v, int k) {
        unsigned su = __float_as_uint(v);
        su = (su & 0x80000000u) ? ~su : (su | 0x80000000u);
        return ((unsigned long long)su << 32) | (unsigned)k;
    };
    __syncthreads();   // done reading codebook before aliasing overwrite
#pragma unroll
    for (int j = 0; j < TPT; ++j)
        smem[s * TOKS_PER_BLOCK + j * 64 + lane] = mkkey(best[j], bi[j]);
    __syncthreads();

    // waves 0..3 finalize token group j==s (xs[j] depends only on lane, so
    // wave s holds group s's vectors); waves 4..7 idle past this point.
    if (s < TPT) {
        const int tok = s * 64 + lane;
        unsigned long long m = smem[tok];
#pragma unroll
        for (int r = 1; r < NSPLIT; ++r) {
            unsigned long long v = smem[r * TOKS_PER_BLOCK + tok];
            m = v < m ? v : m;
        }
        const int bid = (int)(m & 0xffffffffULL);
        unsigned eu = (unsigned)(m >> 32);
        unsigned orig = (eu & 0x80000000u) ? (eu ^ 0x80000000u) : ~eu;
        const float bsc = __uint_as_float(orig);
        const int t = tbase + tok;

        // pick xs[s] via uniform unrolled branch (constant indices only)
        float xv[DIM];
#pragma unroll
        for (int j = 0; j < TPT; ++j)
            if (j == s) {
#pragma unroll
                for (int d = 0; d < DIM; ++d) xv[d] = xs[j][d];
            }

        const float4* wrow = (const float4*)(cb + (size_t)bid * DIM);  // 16B-aligned 48B rows
        float4 q0 = wrow[0], q1 = wrow[1], q2 = wrow[2];
        float qs[DIM] = {q0.x, q0.y, q0.z, q0.w, q1.x, q1.y, q1.z, q1.w,
                         q2.x, q2.y, q2.z, q2.w};

        float4* qo = (float4*)(out + (size_t)t * DIM);
        float4 r0, r1, r2;
        r0.x = xv[0] + (qs[0] - xv[0]);    r0.y = xv[1] + (qs[1] - xv[1]);
        r0.z = xv[2] + (qs[2] - xv[2]);    r0.w = xv[3] + (qs[3] - xv[3]);
        r1.x = xv[4] + (qs[4] - xv[4]);    r1.y = xv[5] + (qs[5] - xv[5]);
        r1.z = xv[6] + (qs[6] - xv[6]);    r1.w = xv[7] + (qs[7] - xv[7]);
        r2.x = xv[8] + (qs[8] - xv[8]);    r2.y = xv[9] + (qs[9] - xv[9]);
        r2.z = xv[10] + (qs[10] - xv[10]); r2.w = xv[11] + (qs[11] - xv[11]);
        qo[0] = r0; qo[1] = r1; qo[2] = r2;

        out[QSIZE + t] = (float)bid;

        // loss: sum_d(q-x)^2 == best score (~1e-8 rel apart; threshold ~2%)
        float ls = bsc * (1.25f / (float)QSIZE);
#pragma unroll
        for (int off = 32; off > 0; off >>= 1) ls += __shfl_down(ls, off);
        if (lane == 0) atomicAdd(out + QSIZE + NTOK, ls);
    }
}
} // namespace

extern "C" void kernel_launch(void* const* d_in, const int* in_sizes, int n_in,
                              void* d_out, int out_size, void* d_ws, size_t ws_size,
                              hipStream_t stream) {
    const float* x  = (const float*)d_in[0];
    const float* cb = (const float*)d_in[1];
    float* out = (float*)d_out;
    float* pk  = (float*)d_ws;   // 26.6 KB workspace

    pack_cb<<<2, 256, 0, stream>>>(cb, pk, out);
    vq_main<<<NBLK, 512, 0, stream>>>(x, cb, pk, out);
}

// Round 8
// 93.893 us; speedup vs baseline: 1.2286x; 1.1471x over previous
//
#include <hip/hip_runtime.h>
#include <math.h>

// VQ quantizer: x [512,256,12] fp32, codebook [512,12] fp32.
// Outputs (concat fp32): quantized_st [512*256*12], indices-as-float [512*256], loss [1].
namespace {
constexpr int KCB   = 512;
constexpr int DIM   = 12;
constexpr int NTOK  = 512 * 256;       // 131072
constexpr int QSIZE = NTOK * DIM;      // 1572864
constexpr int NSPLIT = 8;              // waves per block == K chunks
constexpr int KCHUNK = KCB / NSPLIT;   // 64 codes per wave
constexpr int TPT    = 4;              // tokens/thread (fits 128-VGPR alloc, no spills: R7)
constexpr int TOKS_PER_BLOCK = 64 * TPT;        // 256
constexpr int NBLK   = NTOK / TOKS_PER_BLOCK;   // 512 blocks x 512 thr
constexpr int WVEC_FLOATS = KCB * DIM;          // 6144 (tight 48B rows)
constexpr int CB_FLOATS   = WVEC_FLOATS + KCB;  // + w2[512] = 6656 floats
constexpr int CB_F4       = CB_FLOATS / 4;      // 1664
// shared array: staging (6656 fl) + 8 pad floats for the harmless end-of-chunk
// prefetch of "code 512"/w2[512]; also covers 8x256 u64 reduction (16 KB).
constexpr int SMEM_U64    = 3333;               // 26664 B
constexpr int PARTIALS_OFF = 8192;              // float offset of per-block loss partials in ws

// ws layout: [wvec 512x12 tight][w2 512] ... [partials 512 @ 8192]
__global__ __launch_bounds__(256) void pack_cb(const float* __restrict__ cb,
                                               float* __restrict__ ws) {
    int k = blockIdx.x * blockDim.x + threadIdx.x;
    if (k >= KCB) return;
    float w[DIM];
#pragma unroll
    for (int d = 0; d < DIM; ++d) w[d] = cb[k * DIM + d];
    float w2 = 0.f;
#pragma unroll
    for (int d = 0; d < DIM; ++d) w2 += w[d] * w[d];   // same rounding as R1-R7
#pragma unroll
    for (int d = 0; d < DIM; ++d) ws[k * DIM + d] = w[d];
    ws[WVEC_FLOATS + k] = w2;
}

// EXACT score sequence validated R1-R7 (absmax 0.0 vs numpy). Do not reorder.
__device__ inline float code_score(const float (&xv)[DIM], float x2,
                                   const float4& c0, const float4& c1,
                                   const float4& c2, float w2k) {
    float xw = 0.f;
    xw = fmaf(xv[0],  c0.x, xw);
    xw = fmaf(xv[1],  c0.y, xw);
    xw = fmaf(xv[2],  c0.z, xw);
    xw = fmaf(xv[3],  c0.w, xw);
    xw = fmaf(xv[4],  c1.x, xw);
    xw = fmaf(xv[5],  c1.y, xw);
    xw = fmaf(xv[6],  c1.z, xw);
    xw = fmaf(xv[7],  c1.w, xw);
    xw = fmaf(xv[8],  c2.x, xw);
    xw = fmaf(xv[9],  c2.y, xw);
    xw = fmaf(xv[10], c2.z, xw);
    xw = fmaf(xv[11], c2.w, xw);
    return fmaf(-2.f, xw, x2) + w2k;
}

// Block = 256 tokens x 8 K-splits. R7 diagnosis: waves convoyed on clumped
// ds_reads + full lgkmcnt drains (VALUBusy 34%, wall 3x VALU issue). Fix:
// explicit 2-code double buffer — prefetch code k+1 while scoring code k;
// DS returns IN-ORDER so the compiler's partial lgkmcnt waits only the
// consumed buffer. Registers: xs48 + 2x13 buf + 12 state + addr ~= 105 < 128.
__global__ __launch_bounds__(512, 2) void vq_main(const float* __restrict__ x,
                                                  const float* __restrict__ cb,
                                                  const float* __restrict__ pk,
                                                  float* __restrict__ out,
                                                  float* __restrict__ partials) {
    __shared__ unsigned long long smem[SMEM_U64];
    __shared__ float lred[TPT];
    float* lds = (float*)smem;
    const int tid  = threadIdx.x;
    const int lane = tid & 63;
    const int s = __builtin_amdgcn_readfirstlane(tid >> 6);  // K-chunk id
    const int tbase = blockIdx.x * TOKS_PER_BLOCK;

    // stage packed codebook global->LDS (coalesced float4)
    {
        float4* l4 = (float4*)lds;
        const float4* g4 = (const float4*)pk;
        for (int i = tid; i < CB_F4; i += 512) l4[i] = g4[i];
    }

    // this thread's 4 tokens (lane-contiguous 48B rows)
    float xs[TPT][DIM];
    float x2[TPT];
#pragma unroll
    for (int j = 0; j < TPT; ++j) {
        const float4* xp = (const float4*)(x + (size_t)(tbase + j * 64 + lane) * DIM);
        float4 a0 = xp[0], a1 = xp[1], a2 = xp[2];
        xs[j][0] = a0.x; xs[j][1] = a0.y; xs[j][2]  = a0.z; xs[j][3]  = a0.w;
        xs[j][4] = a1.x; xs[j][5] = a1.y; xs[j][6]  = a1.z; xs[j][7]  = a1.w;
        xs[j][8] = a2.x; xs[j][9] = a2.y; xs[j][10] = a2.z; xs[j][11] = a2.w;
        float t2 = 0.f;
#pragma unroll
        for (int d = 0; d < DIM; ++d) t2 = fmaf(xs[j][d], xs[j][d], t2);
        x2[j] = t2;
    }

    __syncthreads();   // codebook resident

    float best[TPT];
    int   bi[TPT];
#pragma unroll
    for (int j = 0; j < TPT; ++j) { best[j] = INFINITY; bi[j] = 0; }

    const int k0 = s * KCHUNK;
    const float* w2v = lds + WVEC_FLOATS;

    // ---- software-pipelined scan: 2-code double buffer ----
    float4 A0, A1, A2; float w2A;
    float4 B0, B1, B2; float w2B;
    {
        const float* c = lds + (size_t)k0 * DIM;
        A0 = *(const float4*)(c + 0);
        A1 = *(const float4*)(c + 4);
        A2 = *(const float4*)(c + 8);
        w2A = w2v[k0];
    }
#pragma unroll 4
    for (int kk = 0; kk < KCHUNK; kk += 2) {
        {   // prefetch odd code kk+1 into B (flies during A's compute)
            const float* c = lds + (size_t)(k0 + kk + 1) * DIM;
            B0 = *(const float4*)(c + 0);
            B1 = *(const float4*)(c + 4);
            B2 = *(const float4*)(c + 8);
            w2B = w2v[k0 + kk + 1];
        }
        {   // score even code kk with A
            const int k = k0 + kk;
#pragma unroll
            for (int j = 0; j < TPT; ++j) {
                float d = code_score(xs[j], x2[j], A0, A1, A2, w2A);
                bool c = d < best[j];          // strict < => first occurrence
                best[j] = c ? d : best[j];
                bi[j]   = c ? k : bi[j];
            }
        }
        {   // prefetch next even code kk+2 into A (kk+2==KCHUNK on last iter:
            // reads the in-bounds pad region — loaded but never scored)
            const float* c = lds + (size_t)(k0 + kk + 2) * DIM;
            A0 = *(const float4*)(c + 0);
            A1 = *(const float4*)(c + 4);
            A2 = *(const float4*)(c + 8);
            w2A = w2v[k0 + kk + 2];
        }
        {   // score odd code kk+1 with B
            const int k = k0 + kk + 1;
#pragma unroll
            for (int j = 0; j < TPT; ++j) {
                float d = code_score(xs[j], x2[j], B0, B1, B2, w2B);
                bool c = d < best[j];
                best[j] = c ? d : best[j];
                bi[j]   = c ? k : bi[j];
            }
        }
    }

    // cross-wave argmin: u64 (monotone(score), k) unsigned-min == exact
    // lexicographic first-occurrence argmin (validated R2-R7).
    auto mkkey = [](float v, int k) {
        unsigned su = __float_as_uint(v);
        su = (su & 0x80000000u) ? ~su : (su | 0x80000000u);
        return ((unsigned long long)su << 32) | (unsigned)k;
    };
    __syncthreads();   // done reading codebook before aliasing overwrite
#pragma unroll
    for (int j = 0; j < TPT; ++j)
        smem[s * TOKS_PER_BLOCK + j * 64 + lane] = mkkey(best[j], bi[j]);
    __syncthreads();

    // waves 0..3 finalize token group j==s (they hold xs[s] for those tokens)
    if (s < TPT) {
        const int tok = s * 64 + lane;
        unsigned long long m = smem[tok];
#pragma unroll
        for (int r = 1; r < NSPLIT; ++r) {
            unsigned long long v = smem[r * TOKS_PER_BLOCK + tok];
            m = v < m ? v : m;
        }
        const int bid = (int)(m & 0xffffffffULL);
        unsigned eu = (unsigned)(m >> 32);
        unsigned orig = (eu & 0x80000000u) ? (eu ^ 0x80000000u) : ~eu;
        const float bsc = __uint_as_float(orig);
        const int t = tbase + tok;

        float xv[DIM];
#pragma unroll
        for (int j = 0; j < TPT; ++j)
            if (j == s) {
#pragma unroll
                for (int d = 0; d < DIM; ++d) xv[d] = xs[j][d];
            }

        const float4* wrow = (const float4*)(cb + (size_t)bid * DIM);
        float4 q0 = wrow[0], q1 = wrow[1], q2 = wrow[2];
        float qs[DIM] = {q0.x, q0.y, q0.z, q0.w, q1.x, q1.y, q1.z, q1.w,
                         q2.x, q2.y, q2.z, q2.w};

        float4* qo = (float4*)(out + (size_t)t * DIM);
        float4 r0, r1, r2;
        r0.x = xv[0] + (qs[0] - xv[0]);    r0.y = xv[1] + (qs[1] - xv[1]);
        r0.z = xv[2] + (qs[2] - xv[2]);    r0.w = xv[3] + (qs[3] - xv[3]);
        r1.x = xv[4] + (qs[4] - xv[4]);    r1.y = xv[5] + (qs[5] - xv[5]);
        r1.z = xv[6] + (qs[6] - xv[6]);    r1.w = xv[7] + (qs[7] - xv[7]);
        r2.x = xv[8] + (qs[8] - xv[8]);    r2.y = xv[9] + (qs[9] - xv[9]);
        r2.z = xv[10] + (qs[10] - xv[10]); r2.w = xv[11] + (qs[11] - xv[11]);
        qo[0] = r0; qo[1] = r1; qo[2] = r2;

        out[QSIZE + t] = (float)bid;

        // loss partial: sum_d(q-x)^2 == best score (~1e-8 rel; thr ~2%).
        // NO atomics: per-wave shuffle sum -> per-block partial in ws.
        float ls = bsc * (1.25f / (float)QSIZE);
#pragma unroll
        for (int off = 32; off > 0; off >>= 1) ls += __shfl_down(ls, off);
        if (lane == 0) lred[s] = ls;
    }
    __syncthreads();
    if (tid == 0)
        partials[blockIdx.x] = (lred[0] + lred[1]) + (lred[2] + lred[3]);
}

// 512 partials -> loss, single block, no atomics.
__global__ __launch_bounds__(512) void reduce_loss(const float* __restrict__ partials,
                                                   float* __restrict__ out) {
    __shared__ float r[8];
    float v = partials[threadIdx.x];
#pragma unroll
    for (int off = 32; off > 0; off >>= 1) v += __shfl_down(v, off);
    if ((threadIdx.x & 63) == 0) r[threadIdx.x >> 6] = v;
    __syncthreads();
    if (threadIdx.x == 0) {
        float t = 0.f;
#pragma unroll
        for (int i = 0; i < 8; ++i) t += r[i];
        out[QSIZE + NTOK] = t;
    }
}
} // namespace

extern "C" void kernel_launch(void* const* d_in, const int* in_sizes, int n_in,
                              void* d_out, int out_size, void* d_ws, size_t ws_size,
                              hipStream_t stream) {
    const float* x  = (const float*)d_in[0];
    const float* cb = (const float*)d_in[1];
    float* out = (float*)d_out;
    float* pk  = (float*)d_ws;                    // packed codebook
    float* partials = (float*)d_ws + PARTIALS_OFF; // 512 block partials

    pack_cb<<<2, 256, 0, stream>>>(cb, pk);
    vq_main<<<NBLK, 512, 0, stream>>>(x, cb, pk, out, partials);
    reduce_loss<<<1, 512, 0, stream>>>(partials, out);
}